// Round 2
// baseline (2732.573 us; speedup 1.0000x reference)
//
#include <hip/hip_runtime.h>

// BiLSTM (diagonal, PixelRNN-style) on MI355X.
// R1: persistent scan kernel. 512 blocks = 32 groups (batch x stream) x 16
// tiles; per-group device barrier between steps. Weights/hmap/lc live in
// registers across all 32 steps; only lh round-trips global (XCD-local).

using bf16   = __bf16;
using bf16x8 = __attribute__((ext_vector_type(8))) __bf16;
using f32x4  = __attribute__((ext_vector_type(4))) float;

__device__ __forceinline__ float sigf(float x) {
  return __builtin_amdgcn_rcpf(1.0f + __expf(-x));
}
__device__ __forceinline__ float tanh_fast(float x) {
  return 2.0f * __builtin_amdgcn_rcpf(1.0f + __expf(-2.0f * x)) - 1.0f;
}
__device__ __forceinline__ bf16x8 bzero8() {
  bf16x8 v;
#pragma unroll
  for (int e = 0; e < 8; ++e) v[e] = (bf16)0.0f;
  return v;
}
__device__ __forceinline__ float bf_lo(unsigned u) { return __uint_as_float(u << 16); }
__device__ __forceinline__ float bf_hi(unsigned u) { return __uint_as_float(u & 0xffff0000u); }

// ---------------- prep: weights -> bf16, [n][k] layouts ----------------
__global__ void prep_kernel(const float* __restrict__ w_i2s,
                            const float* __restrict__ w_left,
                            const float* __restrict__ w_right,
                            const float* __restrict__ w_skip,
                            bf16* __restrict__ WnI, bf16* __restrict__ WnL,
                            bf16* __restrict__ WnR, bf16* __restrict__ WnS) {
  int t = blockIdx.x * 256 + threadIdx.x;
  if (t < 32768) {
    WnI[t] = (bf16)w_i2s[t];  // [256][128] o-major == desired [n][k]
    int o = t >> 7, k = t & 127;
    // k<64: tap0 (h-1, w+-1) -> w[:,:,0]; k>=64: tap1 (h, w+-1) -> w[:,:,1]
    int src = (k < 64) ? (o * 128 + k * 2) : (o * 128 + (k - 64) * 2 + 1);
    WnL[t] = (bf16)w_left[src];
    WnR[t] = (bf16)w_right[src];
    if (t < 8192) WnS[t] = (bf16)w_skip[t];  // [128][64]
  }
}

// ---------------- hmap = x @ w_i2s^T : M=16384,K=128,N=256 ----------------
__global__ __launch_bounds__(256, 2)
void hmap_kernel(const float* __restrict__ x, const bf16* __restrict__ Wn,
                 bf16* __restrict__ hmap) {
  __shared__ __align__(16) bf16 At[64 * 128];  // XOR-swizzled
  const int tile = blockIdx.x;  // 256 tiles: 64 px each (2 rows of one batch)
  const int b = tile >> 4, h0 = (tile & 15) << 1;
  const int t = threadIdx.x;
  const float* xb = x + (size_t)(b * 128) * 1024 + h0 * 32;
#pragma unroll
  for (int i = 0; i < 8; ++i) {
    int idx = t + 256 * i;          // [0,2048)
    int c = idx >> 4, m4 = idx & 15;
    f32x4 v = *(const f32x4*)(xb + (size_t)c * 1024 + m4 * 4);
#pragma unroll
    for (int e = 0; e < 4; ++e) {
      int m = m4 * 4 + e;
      int kb = (c * 2) ^ ((m & 7) << 4);
      *(bf16*)((char*)At + m * 256 + kb) = (bf16)v[e];
    }
  }
  __syncthreads();
  const int wv = t >> 6, l = t & 63;
  const int l15 = l & 15, lq = l >> 4;
  bf16x8 bfrag[4][4];
#pragma unroll
  for (int q = 0; q < 4; ++q)
#pragma unroll
    for (int kk = 0; kk < 4; ++kk)
      bfrag[q][kk] =
          *(const bf16x8*)(Wn + (q * 64 + wv * 16 + l15) * 128 + kk * 32 + lq * 8);
  f32x4 acc[4][4];
  const f32x4 fz = {0.f, 0.f, 0.f, 0.f};
#pragma unroll
  for (int ms = 0; ms < 4; ++ms)
#pragma unroll
    for (int q = 0; q < 4; ++q) acc[ms][q] = fz;
#pragma unroll
  for (int kk = 0; kk < 4; ++kk) {
#pragma unroll
    for (int ms = 0; ms < 4; ++ms) {
      int m = ms * 16 + l15;
      int kb = ((kk * 32 + lq * 8) * 2) ^ ((m & 7) << 4);
      bf16x8 a = *(const bf16x8*)((const char*)At + m * 256 + kb);
#pragma unroll
      for (int q = 0; q < 4; ++q)
        acc[ms][q] =
            __builtin_amdgcn_mfma_f32_16x16x32_bf16(a, bfrag[q][kk], acc[ms][q], 0, 0, 0);
    }
  }
  const int pix0 = tile * 64;
#pragma unroll
  for (int ms = 0; ms < 4; ++ms)
#pragma unroll
    for (int q = 0; q < 4; ++q)
#pragma unroll
      for (int j = 0; j < 4; ++j) {
        int p = pix0 + ms * 16 + lq * 4 + j;
        int n = q * 64 + wv * 16 + l15;
        hmap[(size_t)p * 256 + n] = (bf16)acc[ms][q][j];
      }
}

// ---------------- persistent scan: all 32 steps, both streams ----------------
// blk = tl*32 + g; g = batch*2 + stream (16 blocks per group, same XCD under
// round-robin block->XCD mapping -- perf heuristic only).
__global__ __launch_bounds__(256, 2)
void scan_kernel(bf16* __restrict__ lhL0, bf16* __restrict__ lhL1,
                 bf16* __restrict__ lhR0, bf16* __restrict__ lhR1,
                 const bf16* __restrict__ hmap,
                 const bf16* __restrict__ WnL, const bf16* __restrict__ WnR,
                 const float* __restrict__ bL, const float* __restrict__ bR,
                 unsigned* __restrict__ ctr) {
  __shared__ __align__(16) bf16 At[64 * 128];
  const int blk = blockIdx.x;
  const int g = blk & 31;      // group id (batch*2 + stream)
  const int tl = blk >> 5;     // 2-row tile within batch [0,16)
  const bool right = (g & 1) != 0;
  const int b = g >> 1;
  const int h0 = tl << 1;
  const int t = threadIdx.x;
  const int dw = right ? 1 : -1;
  bf16* p0 = right ? lhR0 : lhL0;
  bf16* p1 = right ? lhR1 : lhL1;
  const bf16* __restrict__ Wn = right ? WnR : WnL;
  const float* __restrict__ bias = right ? bR : bL;
  unsigned* myctr = ctr + g * 32;  // 128B-spaced counters

  const int wv = t >> 6, l = t & 63;
  const int l15 = l & 15, lq = l >> 4;
  const int c = wv * 16 + l15;        // channel this lane owns
  const int pix0 = b * 1024 + tl * 64;

  // ---- loop-invariant state into registers ----
  float bq[4];
#pragma unroll
  for (int q = 0; q < 4; ++q) bq[q] = bias[q * 64 + c];
  bf16x8 bfrag[4][4];
#pragma unroll
  for (int q = 0; q < 4; ++q)
#pragma unroll
    for (int kk = 0; kk < 4; ++kk)
      bfrag[q][kk] = *(const bf16x8*)(Wn + (q * 64 + c) * 128 + kk * 32 + lq * 8);
  // hmap gather: 16 px x 4 gates, packed bf16 pairs (32 VGPR)
  unsigned hmp[4][4][2];
  const unsigned short* hm16 = (const unsigned short*)hmap;
#pragma unroll
  for (int ms = 0; ms < 4; ++ms)
#pragma unroll
    for (int q = 0; q < 4; ++q)
#pragma unroll
      for (int j2 = 0; j2 < 2; ++j2) {
        unsigned lo = hm16[(size_t)(pix0 + ms * 16 + lq * 4 + j2 * 2) * 256 + q * 64 + c];
        unsigned hi = hm16[(size_t)(pix0 + ms * 16 + lq * 4 + j2 * 2 + 1) * 256 + q * 64 + c];
        hmp[ms][q][j2] = lo | (hi << 16);
      }
  float lc_r[4][4];
#pragma unroll
  for (int ms = 0; ms < 4; ++ms)
#pragma unroll
    for (int j = 0; j < 4; ++j) lc_r[ms][j] = 0.0f;

  for (int s = 0; s < 32; ++s) {
    const bf16* lin = (s & 1) ? p1 : p0;
    bf16* lout = (s & 1) ? p0 : p1;
    // ---- stage A: [m][k] k<64 = lh(h-1,w+dw), k>=64 = lh(h,w+dw); OOB -> 0
#pragma unroll
    for (int i = 0; i < 4; ++i) {
      int idx = t + 256 * i;  // [0,1024)
      int tap = idx >> 9, rem = idx & 511, m = rem >> 3, c8 = rem & 7;
      int h = h0 + (m >> 5), w = m & 31;
      int wsrc = w + dw;
      int hsrc = (tap == 0) ? h - 1 : h;
      bf16x8 v;
      if (wsrc < 0 || wsrc > 31 || hsrc < 0)
        v = bzero8();
      else
        v = *(const bf16x8*)(lin + (size_t)((b * 32 + hsrc) * 32 + wsrc) * 64 + c8 * 8);
      int kb = (tap * 128 + c8 * 16) ^ ((m & 7) << 4);
      *(bf16x8*)((char*)At + m * 256 + kb) = v;
    }
    __syncthreads();
    // ---- GEMM
    f32x4 acc[4][4];
    const f32x4 fz = {0.f, 0.f, 0.f, 0.f};
#pragma unroll
    for (int ms = 0; ms < 4; ++ms)
#pragma unroll
      for (int q = 0; q < 4; ++q) acc[ms][q] = fz;
#pragma unroll
    for (int kk = 0; kk < 4; ++kk) {
#pragma unroll
      for (int ms = 0; ms < 4; ++ms) {
        int m = ms * 16 + l15;
        int kb = ((kk * 32 + lq * 8) * 2) ^ ((m & 7) << 4);
        bf16x8 a = *(const bf16x8*)((const char*)At + m * 256 + kb);
#pragma unroll
        for (int q = 0; q < 4; ++q)
          acc[ms][q] =
              __builtin_amdgcn_mfma_f32_16x16x32_bf16(a, bfrag[q][kk], acc[ms][q], 0, 0, 0);
      }
    }
    // ---- epilogue: gates + lc (registers) + lh_out store
#pragma unroll
    for (int ms = 0; ms < 4; ++ms) {
#pragma unroll
      for (int j = 0; j < 4; ++j) {
        int p = pix0 + ms * 16 + lq * 4 + j;
        float pre[4];
#pragma unroll
        for (int q = 0; q < 4; ++q) {
          unsigned u = hmp[ms][q][j >> 1];
          float hv = (j & 1) ? bf_hi(u) : bf_lo(u);
          pre[q] = acc[ms][q][j] + hv + bq[q];
        }
        float og = sigf(pre[0]);
        float fg = sigf(pre[1]);
        float ig = sigf(pre[2]);
        float gg = sigf(pre[3]);
        float lcv = fg * lc_r[ms][j] + ig * gg;
        lc_r[ms][j] = lcv;
        lout[(size_t)p * 64 + c] = (bf16)(og * tanh_fast(lcv));
      }
    }
    // ---- per-group device barrier (signal completion of step s)
    __threadfence();
    __syncthreads();
    if (t == 0)
      __hip_atomic_fetch_add(myctr, 1u, __ATOMIC_RELEASE, __HIP_MEMORY_SCOPE_AGENT);
    if (s != 31) {
      if (t == 0) {
        unsigned tgt = 16u * (unsigned)(s + 1);
        while (__hip_atomic_load(myctr, __ATOMIC_ACQUIRE, __HIP_MEMORY_SCOPE_AGENT) < tgt) {
        }
      }
      __syncthreads();
    }
  }
}

// ---------------- final: out = x + (lhL + shift_down(lhR)) @ w_skip^T + b ----------------
__global__ __launch_bounds__(256, 2)
void final_kernel(const float* __restrict__ x, const bf16* __restrict__ lhL,
                  const bf16* __restrict__ lhR, const bf16* __restrict__ Wn,
                  const float* __restrict__ b_skip, float* __restrict__ out) {
  __shared__ __align__(16) bf16 At[64 * 64];
  __shared__ __align__(16) float smemT[128 * 72];  // [o2][m], padded rows
  const int tile = blockIdx.x;
  const int b = tile >> 4, h0 = (tile & 15) << 1;
  const int t = threadIdx.x;
#pragma unroll
  for (int i = 0; i < 2; ++i) {
    int idx = t + 256 * i;  // [0,512)
    int m = idx >> 3, c8 = idx & 7;
    int h = h0 + (m >> 5), w = m & 31;
    size_t p = (size_t)(b * 32 + h) * 32 + w;
    bf16x8 vL = *(const bf16x8*)(lhL + p * 64 + c8 * 8);
    bf16x8 v;
    if (h > 0) {
      bf16x8 vR = *(const bf16x8*)(lhR + (p - 32) * 64 + c8 * 8);
#pragma unroll
      for (int e = 0; e < 8; ++e) v[e] = (bf16)((float)vL[e] + (float)vR[e]);
    } else {
      v = vL;
    }
    int kb = (c8 * 16) ^ ((m & 7) << 4);
    *(bf16x8*)((char*)At + m * 128 + kb) = v;
  }
  __syncthreads();
  const int wv = t >> 6, l = t & 63;
  const int l15 = l & 15, lq = l >> 4;
  const int c = wv * 16 + l15;
  bf16x8 bfrag[2][2];
#pragma unroll
  for (int q = 0; q < 2; ++q)
#pragma unroll
    for (int kk = 0; kk < 2; ++kk)
      bfrag[q][kk] = *(const bf16x8*)(Wn + (q * 64 + c) * 64 + kk * 32 + lq * 8);
  f32x4 acc[4][2];
  const f32x4 fz = {0.f, 0.f, 0.f, 0.f};
#pragma unroll
  for (int ms = 0; ms < 4; ++ms)
#pragma unroll
    for (int q = 0; q < 2; ++q) acc[ms][q] = fz;
#pragma unroll
  for (int kk = 0; kk < 2; ++kk) {
#pragma unroll
    for (int ms = 0; ms < 4; ++ms) {
      int m = ms * 16 + l15;
      int kb = ((kk * 32 + lq * 8) * 2) ^ ((m & 7) << 4);
      bf16x8 a = *(const bf16x8*)((const char*)At + m * 128 + kb);
#pragma unroll
      for (int q = 0; q < 2; ++q)
        acc[ms][q] =
            __builtin_amdgcn_mfma_f32_16x16x32_bf16(a, bfrag[q][kk], acc[ms][q], 0, 0, 0);
    }
  }
  float bsk[2];
#pragma unroll
  for (int q = 0; q < 2; ++q) bsk[q] = b_skip[q * 64 + c];
#pragma unroll
  for (int ms = 0; ms < 4; ++ms)
#pragma unroll
    for (int q = 0; q < 2; ++q)
#pragma unroll
      for (int j = 0; j < 4; ++j) {
        int m = ms * 16 + lq * 4 + j;
        int n = q * 64 + c;
        smemT[n * 72 + m] = acc[ms][q][j] + bsk[q];
      }
  __syncthreads();
  const float* xb = x + (size_t)(b * 128) * 1024 + h0 * 32;
  float* ob = out + (size_t)(b * 128) * 1024 + h0 * 32;
#pragma unroll
  for (int i = 0; i < 8; ++i) {
    int idx = t + 256 * i;  // [0,2048)
    int o2 = idx >> 4, m4 = idx & 15;
    f32x4 s = *(const f32x4*)(&smemT[o2 * 72 + m4 * 4]);
    f32x4 xv = *(const f32x4*)(xb + (size_t)o2 * 1024 + m4 * 4);
#pragma unroll
    for (int e = 0; e < 4; ++e) s[e] += xv[e];
    *(f32x4*)(ob + (size_t)o2 * 1024 + m4 * 4) = s;
  }
}

extern "C" void kernel_launch(void* const* d_in, const int* in_sizes, int n_in,
                              void* d_out, int out_size, void* d_ws, size_t ws_size,
                              hipStream_t stream) {
  const float* x       = (const float*)d_in[0];
  const float* w_i2s   = (const float*)d_in[1];
  const float* w_left  = (const float*)d_in[2];
  const float* b_left  = (const float*)d_in[3];
  const float* w_right = (const float*)d_in[4];
  const float* b_right = (const float*)d_in[5];
  const float* w_skip  = (const float*)d_in[6];
  const float* b_skip  = (const float*)d_in[7];
  float* out = (float*)d_out;
  char* ws = (char*)d_ws;

  // ws layout (bytes)
  bf16*     lhL0 = (bf16*)(ws + 0x000000);   // 2 MB (zeroed)
  bf16*     lhR0 = (bf16*)(ws + 0x200000);   // 2 MB (zeroed)
  unsigned* ctr  = (unsigned*)(ws + 0x400000); // 4 KB (zeroed)
  bf16*     lhL1 = (bf16*)(ws + 0x500000);   // 2 MB
  bf16*     lhR1 = (bf16*)(ws + 0x700000);   // 2 MB
  bf16*     hmap = (bf16*)(ws + 0x900000);   // 8 MB
  bf16*     WnI  = (bf16*)(ws + 0x1100000);  // 64 KB
  bf16*     WnL  = (bf16*)(ws + 0x1110000);
  bf16*     WnR  = (bf16*)(ws + 0x1120000);
  bf16*     WnS  = (bf16*)(ws + 0x1130000);

  // zero initial lh state + barrier counters (one contiguous region)
  hipMemsetAsync(ws, 0, 0x401000, stream);
  prep_kernel<<<128, 256, 0, stream>>>(w_i2s, w_left, w_right, w_skip, WnI, WnL, WnR, WnS);
  hmap_kernel<<<256, 256, 0, stream>>>(x, WnI, hmap);
  scan_kernel<<<512, 256, 0, stream>>>(lhL0, lhL1, lhR0, lhR1, hmap,
                                       WnL, WnR, b_left, b_right, ctr);
  // after 32 steps, final state is back in buffer 0
  final_kernel<<<256, 256, 0, stream>>>(x, lhL0, lhR0, WnS, b_skip, out);
}

// Round 3
// 527.254 us; speedup vs baseline: 5.1826x; 5.1826x over previous
//
#include <hip/hip_runtime.h>

// BiLSTM (diagonal, PixelRNN-style) on MI355X.
// R2: back to launch-per-step family (R1's device-scope barriers cost 85us/step).
// k=2 steps per launch via halo recompute: block owns 2 rows + 1 halo row.
// GEMM1 M=96 from global lh; lh_s stays in registers and is scatter-written
// into a second LDS A-tile; GEMM2 M=64 produces lh_{s+1} -> global.
// lc double-buffered in global, register-resident between the two steps.
// hmap packed [p][c][4gates] so the epilogue reads one 8B chunk per pixel.

using bf16   = __bf16;
using bf16x8 = __attribute__((ext_vector_type(8))) __bf16;
using f32x4  = __attribute__((ext_vector_type(4))) float;

__device__ __forceinline__ float sigf(float x) {
  return __builtin_amdgcn_rcpf(1.0f + __expf(-x));
}
__device__ __forceinline__ float tanh_fast(float x) {
  return 2.0f * __builtin_amdgcn_rcpf(1.0f + __expf(-2.0f * x)) - 1.0f;
}
__device__ __forceinline__ bf16x8 bzero8() {
  bf16x8 v;
#pragma unroll
  for (int e = 0; e < 8; ++e) v[e] = (bf16)0.0f;
  return v;
}
__device__ __forceinline__ unsigned short f2bu(float f) {
  bf16 b = (bf16)f;
  return __builtin_bit_cast(unsigned short, b);
}
__device__ __forceinline__ float bu2f(unsigned short u) {
  return __uint_as_float(((unsigned)u) << 16);
}

// ---------------- prep: weights -> bf16, [n][k] layouts ----------------
__global__ void prep_kernel(const float* __restrict__ w_i2s,
                            const float* __restrict__ w_left,
                            const float* __restrict__ w_right,
                            const float* __restrict__ w_skip,
                            bf16* __restrict__ WnI, bf16* __restrict__ WnL,
                            bf16* __restrict__ WnR, bf16* __restrict__ WnS) {
  int t = blockIdx.x * 256 + threadIdx.x;
  if (t < 32768) {
    WnI[t] = (bf16)w_i2s[t];  // [256][128] o-major == desired [n][k]
    int o = t >> 7, k = t & 127;
    // k<64: tap0 (h-1, w+-1) -> w[:,:,0]; k>=64: tap1 (h, w+-1) -> w[:,:,1]
    int src = (k < 64) ? (o * 128 + k * 2) : (o * 128 + (k - 64) * 2 + 1);
    WnL[t] = (bf16)w_left[src];
    WnR[t] = (bf16)w_right[src];
    if (t < 8192) WnS[t] = (bf16)w_skip[t];  // [128][64]
  }
}

// ------- hmap2 = pack(x @ w_i2s^T) : [p][c][4 gates] ushort4 (bf16 bits) -------
__global__ __launch_bounds__(256, 2)
void hmap_kernel(const float* __restrict__ x, const bf16* __restrict__ Wn,
                 ushort* __restrict__ hmap2) {
  __shared__ __align__(16) bf16 At[64 * 128];  // XOR-swizzled
  const int tile = blockIdx.x;  // 256 tiles: 64 px each (2 rows of one batch)
  const int b = tile >> 4, h0 = (tile & 15) << 1;
  const int t = threadIdx.x;
  const float* xb = x + (size_t)(b * 128) * 1024 + h0 * 32;
#pragma unroll
  for (int i = 0; i < 8; ++i) {
    int idx = t + 256 * i;          // [0,2048)
    int c = idx >> 4, m4 = idx & 15;
    f32x4 v = *(const f32x4*)(xb + (size_t)c * 1024 + m4 * 4);
#pragma unroll
    for (int e = 0; e < 4; ++e) {
      int m = m4 * 4 + e;
      int kb = (c * 2) ^ ((m & 7) << 4);
      *(bf16*)((char*)At + m * 256 + kb) = (bf16)v[e];
    }
  }
  __syncthreads();
  const int wv = t >> 6, l = t & 63;
  const int l15 = l & 15, lq = l >> 4;
  const int c = wv * 16 + l15;
  bf16x8 bfrag[4][4];
#pragma unroll
  for (int q = 0; q < 4; ++q)
#pragma unroll
    for (int kk = 0; kk < 4; ++kk)
      bfrag[q][kk] = *(const bf16x8*)(Wn + (q * 64 + c) * 128 + kk * 32 + lq * 8);
  f32x4 acc[4][4];
  const f32x4 fz = {0.f, 0.f, 0.f, 0.f};
#pragma unroll
  for (int ms = 0; ms < 4; ++ms)
#pragma unroll
    for (int q = 0; q < 4; ++q) acc[ms][q] = fz;
#pragma unroll
  for (int kk = 0; kk < 4; ++kk) {
#pragma unroll
    for (int ms = 0; ms < 4; ++ms) {
      int m = ms * 16 + l15;
      int kb = ((kk * 32 + lq * 8) * 2) ^ ((m & 7) << 4);
      bf16x8 a = *(const bf16x8*)((const char*)At + m * 256 + kb);
#pragma unroll
      for (int q = 0; q < 4; ++q)
        acc[ms][q] =
            __builtin_amdgcn_mfma_f32_16x16x32_bf16(a, bfrag[q][kk], acc[ms][q], 0, 0, 0);
    }
  }
  const int pix0 = tile * 64;
#pragma unroll
  for (int ms = 0; ms < 4; ++ms)
#pragma unroll
    for (int j = 0; j < 4; ++j) {
      int p = pix0 + ms * 16 + lq * 4 + j;
      ushort4 hv;
      hv.x = f2bu(acc[ms][0][j]);
      hv.y = f2bu(acc[ms][1][j]);
      hv.z = f2bu(acc[ms][2][j]);
      hv.w = f2bu(acc[ms][3][j]);
      ((ushort4*)hmap2)[(size_t)p * 64 + c] = hv;
    }
}

// ---------------- two scan steps per launch ----------------
// blocks [0,256): left; [256,512): right. Block owns rows {2tl, 2tl+1} and
// recomputes halo row 2tl-1 for step s so step s+1 needs no communication.
__global__ __launch_bounds__(256, 2)
void step2_kernel(const bf16* __restrict__ lhLin, bf16* __restrict__ lhLout,
                  const bf16* __restrict__ lhRin, bf16* __restrict__ lhRout,
                  const float* __restrict__ lcLin, float* __restrict__ lcLout,
                  const float* __restrict__ lcRin, float* __restrict__ lcRout,
                  const ushort* __restrict__ hmap2,
                  const bf16* __restrict__ WnL, const bf16* __restrict__ WnR,
                  const float* __restrict__ bL, const float* __restrict__ bR) {
  __shared__ __align__(16) bf16 At1[96 * 128];  // step s A-tile (rows 2tl-1..2tl+1)
  __shared__ __align__(16) bf16 At2[64 * 128];  // step s+1 A-tile (rows 2tl..2tl+1)
  const int blk = blockIdx.x;
  const bool right = blk >= 256;
  const int tile = right ? blk - 256 : blk;
  const bf16* __restrict__ lin = right ? lhRin : lhLin;
  bf16* __restrict__ lout = right ? lhRout : lhLout;
  const float* __restrict__ lcIn = right ? lcRin : lcLin;
  float* __restrict__ lcOut = right ? lcRout : lcLout;
  const bf16* __restrict__ Wn = right ? WnR : WnL;
  const float* __restrict__ bias = right ? bR : bL;
  const int b = tile >> 4, tl = tile & 15;
  const int t = threadIdx.x;
  const int dw = right ? 1 : -1;

  // zero At2 (boundary slots must be 0; written slots are overwritten below)
#pragma unroll
  for (int i = 0; i < 4; ++i) ((bf16x8*)At2)[t + 256 * i] = bzero8();

  // ---- stage At1: M=96 rows (2tl-1 .. 2tl+1), K=128 (tap0 | tap1)
#pragma unroll
  for (int i = 0; i < 3; ++i) {  // tap0: lh(r-1, w+dw)
    int idx = t + 256 * i;       // [0,768)
    int m = idx >> 3, c8 = idx & 7;
    int w = m & 31, wsrc = w + dw;
    int hsrc = 2 * tl - 2 + (m >> 5);
    bf16x8 v;
    if (wsrc < 0 || wsrc > 31 || hsrc < 0)
      v = bzero8();
    else
      v = *(const bf16x8*)(lin + (size_t)((b * 32 + hsrc) * 32 + wsrc) * 64 + c8 * 8);
    int kb = (c8 * 16) ^ ((m & 7) << 4);
    *(bf16x8*)((char*)At1 + m * 256 + kb) = v;
  }
#pragma unroll
  for (int i = 0; i < 3; ++i) {  // tap1: lh(r, w+dw)
    int idx = t + 256 * i;
    int m = idx >> 3, c8 = idx & 7;
    int w = m & 31, wsrc = w + dw;
    int hsrc = 2 * tl - 1 + (m >> 5);
    bf16x8 v;
    if (wsrc < 0 || wsrc > 31 || hsrc < 0)
      v = bzero8();
    else
      v = *(const bf16x8*)(lin + (size_t)((b * 32 + hsrc) * 32 + wsrc) * 64 + c8 * 8);
    int kb = (128 + c8 * 16) ^ ((m & 7) << 4);
    *(bf16x8*)((char*)At1 + m * 256 + kb) = v;
  }

  const int wv = t >> 6, l = t & 63;
  const int l15 = l & 15, lq = l >> 4;
  const int c = wv * 16 + l15;  // channel this lane owns (gate-interleaved N)
  float bq[4];
#pragma unroll
  for (int q = 0; q < 4; ++q) bq[q] = bias[q * 64 + c];
  bf16x8 bfrag[4][4];
#pragma unroll
  for (int q = 0; q < 4; ++q)
#pragma unroll
    for (int kk = 0; kk < 4; ++kk)
      bfrag[q][kk] = *(const bf16x8*)(Wn + (q * 64 + c) * 128 + kk * 32 + lq * 8);
  // lc for rows 2tl-1..2tl+1 into registers (written by previous launch)
  float lc_r[6][4];
#pragma unroll
  for (int ms = 0; ms < 6; ++ms) {
    int r = 2 * tl - 1 + (ms >> 1);
#pragma unroll
    for (int j = 0; j < 4; ++j) {
      int w = (ms & 1) * 16 + lq * 4 + j;
      long p = (long)b * 1024 + (long)r * 32 + w;  // r=-1 only when tl==0 (guarded below)
      lc_r[ms][j] = (r >= 0) ? lcIn[p * 64 + c] : 0.0f;
    }
  }
  __syncthreads();

  // ---- GEMM1: M=96
  f32x4 acc[6][4];
  const f32x4 fz = {0.f, 0.f, 0.f, 0.f};
#pragma unroll
  for (int ms = 0; ms < 6; ++ms)
#pragma unroll
    for (int q = 0; q < 4; ++q) acc[ms][q] = fz;
#pragma unroll
  for (int kk = 0; kk < 4; ++kk) {
#pragma unroll
    for (int ms = 0; ms < 6; ++ms) {
      int m = ms * 16 + l15;
      int kb = ((kk * 32 + lq * 8) * 2) ^ ((m & 7) << 4);
      bf16x8 a = *(const bf16x8*)((const char*)At1 + m * 256 + kb);
#pragma unroll
      for (int q = 0; q < 4; ++q)
        acc[ms][q] =
            __builtin_amdgcn_mfma_f32_16x16x32_bf16(a, bfrag[q][kk], acc[ms][q], 0, 0, 0);
    }
  }

  // ---- epilogue step s: gates, lc update (regs), scatter lh_s into At2
#pragma unroll
  for (int ms = 0; ms < 6; ++ms) {
    int row = ms >> 1;            // 0..2 within the 3-row group
    int r = 2 * tl - 1 + row;     // absolute row; -1 only for tl==0, ms<2
    bool valid = (r >= 0);
#pragma unroll
    for (int j = 0; j < 4; ++j) {
      int w = (ms & 1) * 16 + lq * 4 + j;
      long p = (long)b * 1024 + (long)r * 32 + w;
      ushort4 hm = ((const ushort4*)hmap2)[p * 64 + c];  // garbage if !valid (in-ws)
      float pre0 = acc[ms][0][j] + bu2f(hm.x) + bq[0];
      float pre1 = acc[ms][1][j] + bu2f(hm.y) + bq[1];
      float pre2 = acc[ms][2][j] + bu2f(hm.z) + bq[2];
      float pre3 = acc[ms][3][j] + bu2f(hm.w) + bq[3];
      float og = sigf(pre0), fg = sigf(pre1), ig = sigf(pre2), gg = sigf(pre3);
      float lcv = fg * lc_r[ms][j] + ig * gg;
      lc_r[ms][j] = lcv;
      float lh = valid ? og * tanh_fast(lcv) : 0.0f;
      bf16 vb = (bf16)lh;
      int w2 = w - dw;  // slot whose (w2+dw) == w
      if (w2 >= 0 && w2 < 32) {
        if (ms >= 2) {  // tap1 slot of own row (rows 2tl..2tl+1)
          int m2 = (row - 1) * 32 + w2;
          *(bf16*)((char*)At2 + m2 * 256 + ((2 * (64 + c)) ^ ((m2 & 7) << 4))) = vb;
        }
        if (ms <= 3) {  // tap0 slot of row below (rows 2tl..2tl+1)
          int m2 = row * 32 + w2;
          *(bf16*)((char*)At2 + m2 * 256 + ((2 * c) ^ ((m2 & 7) << 4))) = vb;
        }
      }
    }
  }
  __syncthreads();

  // ---- GEMM2: M=64
  f32x4 acc2[4][4];
#pragma unroll
  for (int ms = 0; ms < 4; ++ms)
#pragma unroll
    for (int q = 0; q < 4; ++q) acc2[ms][q] = fz;
#pragma unroll
  for (int kk = 0; kk < 4; ++kk) {
#pragma unroll
    for (int ms = 0; ms < 4; ++ms) {
      int m = ms * 16 + l15;
      int kb = ((kk * 32 + lq * 8) * 2) ^ ((m & 7) << 4);
      bf16x8 a = *(const bf16x8*)((const char*)At2 + m * 256 + kb);
#pragma unroll
      for (int q = 0; q < 4; ++q)
        acc2[ms][q] =
            __builtin_amdgcn_mfma_f32_16x16x32_bf16(a, bfrag[q][kk], acc2[ms][q], 0, 0, 0);
    }
  }

  // ---- epilogue step s+1: gates, lc -> global, lh -> global
#pragma unroll
  for (int ms = 0; ms < 4; ++ms) {
    int row2 = ms >> 1;
    int r = 2 * tl + row2;
#pragma unroll
    for (int j = 0; j < 4; ++j) {
      int w = (ms & 1) * 16 + lq * 4 + j;
      long p = (long)b * 1024 + (long)r * 32 + w;
      ushort4 hm = ((const ushort4*)hmap2)[p * 64 + c];
      float pre0 = acc2[ms][0][j] + bu2f(hm.x) + bq[0];
      float pre1 = acc2[ms][1][j] + bu2f(hm.y) + bq[1];
      float pre2 = acc2[ms][2][j] + bu2f(hm.z) + bq[2];
      float pre3 = acc2[ms][3][j] + bu2f(hm.w) + bq[3];
      float og = sigf(pre0), fg = sigf(pre1), ig = sigf(pre2), gg = sigf(pre3);
      float lcv = fg * lc_r[ms + 2][j] + ig * gg;  // lc_s of same pixel
      lcOut[p * 64 + c] = lcv;
      lout[p * 64 + c] = (bf16)(og * tanh_fast(lcv));
    }
  }
}

// ---------------- final: out = x + (lhL + shift_down(lhR)) @ w_skip^T + b ----------------
__global__ __launch_bounds__(256, 2)
void final_kernel(const float* __restrict__ x, const bf16* __restrict__ lhL,
                  const bf16* __restrict__ lhR, const bf16* __restrict__ Wn,
                  const float* __restrict__ b_skip, float* __restrict__ out) {
  __shared__ __align__(16) bf16 At[64 * 64];
  __shared__ __align__(16) float smemT[128 * 72];  // [o2][m], padded rows
  const int tile = blockIdx.x;
  const int b = tile >> 4, h0 = (tile & 15) << 1;
  const int t = threadIdx.x;
#pragma unroll
  for (int i = 0; i < 2; ++i) {
    int idx = t + 256 * i;  // [0,512)
    int m = idx >> 3, c8 = idx & 7;
    int h = h0 + (m >> 5), w = m & 31;
    size_t p = (size_t)(b * 32 + h) * 32 + w;
    bf16x8 vL = *(const bf16x8*)(lhL + p * 64 + c8 * 8);
    bf16x8 v;
    if (h > 0) {
      bf16x8 vR = *(const bf16x8*)(lhR + (p - 32) * 64 + c8 * 8);
#pragma unroll
      for (int e = 0; e < 8; ++e) v[e] = (bf16)((float)vL[e] + (float)vR[e]);
    } else {
      v = vL;
    }
    int kb = (c8 * 16) ^ ((m & 7) << 4);
    *(bf16x8*)((char*)At + m * 128 + kb) = v;
  }
  __syncthreads();
  const int wv = t >> 6, l = t & 63;
  const int l15 = l & 15, lq = l >> 4;
  const int c = wv * 16 + l15;
  bf16x8 bfrag[2][2];
#pragma unroll
  for (int q = 0; q < 2; ++q)
#pragma unroll
    for (int kk = 0; kk < 2; ++kk)
      bfrag[q][kk] = *(const bf16x8*)(Wn + (q * 64 + c) * 64 + kk * 32 + lq * 8);
  f32x4 acc[4][2];
  const f32x4 fz = {0.f, 0.f, 0.f, 0.f};
#pragma unroll
  for (int ms = 0; ms < 4; ++ms)
#pragma unroll
    for (int q = 0; q < 2; ++q) acc[ms][q] = fz;
#pragma unroll
  for (int kk = 0; kk < 2; ++kk) {
#pragma unroll
    for (int ms = 0; ms < 4; ++ms) {
      int m = ms * 16 + l15;
      int kb = ((kk * 32 + lq * 8) * 2) ^ ((m & 7) << 4);
      bf16x8 a = *(const bf16x8*)((const char*)At + m * 128 + kb);
#pragma unroll
      for (int q = 0; q < 2; ++q)
        acc[ms][q] =
            __builtin_amdgcn_mfma_f32_16x16x32_bf16(a, bfrag[q][kk], acc[ms][q], 0, 0, 0);
    }
  }
  float bsk[2];
#pragma unroll
  for (int q = 0; q < 2; ++q) bsk[q] = b_skip[q * 64 + c];
#pragma unroll
  for (int ms = 0; ms < 4; ++ms)
#pragma unroll
    for (int q = 0; q < 2; ++q)
#pragma unroll
      for (int j = 0; j < 4; ++j) {
        int m = ms * 16 + lq * 4 + j;
        int n = q * 64 + c;
        smemT[n * 72 + m] = acc[ms][q][j] + bsk[q];
      }
  __syncthreads();
  const float* xb = x + (size_t)(b * 128) * 1024 + h0 * 32;
  float* ob = out + (size_t)(b * 128) * 1024 + h0 * 32;
#pragma unroll
  for (int i = 0; i < 8; ++i) {
    int idx = t + 256 * i;  // [0,2048)
    int o2 = idx >> 4, m4 = idx & 15;
    f32x4 s = *(const f32x4*)(&smemT[o2 * 72 + m4 * 4]);
    f32x4 xv = *(const f32x4*)(xb + (size_t)o2 * 1024 + m4 * 4);
#pragma unroll
    for (int e = 0; e < 4; ++e) s[e] += xv[e];
    *(f32x4*)(ob + (size_t)o2 * 1024 + m4 * 4) = s;
  }
}

extern "C" void kernel_launch(void* const* d_in, const int* in_sizes, int n_in,
                              void* d_out, int out_size, void* d_ws, size_t ws_size,
                              hipStream_t stream) {
  const float* x       = (const float*)d_in[0];
  const float* w_i2s   = (const float*)d_in[1];
  const float* w_left  = (const float*)d_in[2];
  const float* b_left  = (const float*)d_in[3];
  const float* w_right = (const float*)d_in[4];
  const float* b_right = (const float*)d_in[5];
  const float* w_skip  = (const float*)d_in[6];
  const float* b_skip  = (const float*)d_in[7];
  float* out = (float*)d_out;
  char* ws = (char*)d_ws;

  // ws layout (bytes); total ~32.5 MB
  bf16*   lhL0  = (bf16*)(ws + 0x0000000);   // 2 MB (zeroed)
  bf16*   lhR0  = (bf16*)(ws + 0x0200000);   // 2 MB (zeroed)
  bf16*   lhL1  = (bf16*)(ws + 0x0400000);   // 2 MB
  bf16*   lhR1  = (bf16*)(ws + 0x0600000);   // 2 MB
  float*  lcL0  = (float*)(ws + 0x0800000);  // 4 MB (zeroed)
  float*  lcR0  = (float*)(ws + 0x0C00000);  // 4 MB (zeroed)
  float*  lcL1  = (float*)(ws + 0x1000000);  // 4 MB
  float*  lcR1  = (float*)(ws + 0x1400000);  // 4 MB
  ushort* hmap2 = (ushort*)(ws + 0x1800000); // 8 MB
  bf16*   WnI   = (bf16*)(ws + 0x2000000);   // 64 KB
  bf16*   WnL   = (bf16*)(ws + 0x2010000);
  bf16*   WnR   = (bf16*)(ws + 0x2020000);
  bf16*   WnS   = (bf16*)(ws + 0x2030000);

  // zero initial lh (0x0-0x800000) and lc (0x800000-0x1000000)
  hipMemsetAsync(ws, 0, 0x1000000, stream);
  prep_kernel<<<128, 256, 0, stream>>>(w_i2s, w_left, w_right, w_skip, WnI, WnL, WnR, WnS);
  hmap_kernel<<<256, 256, 0, stream>>>(x, WnI, hmap2);
  for (int i = 0; i < 16; ++i) {
    bf16* li = (i & 1) ? lhL1 : lhL0;
    bf16* lo = (i & 1) ? lhL0 : lhL1;
    bf16* ri = (i & 1) ? lhR1 : lhR0;
    bf16* ro = (i & 1) ? lhR0 : lhR1;
    float* cli = (i & 1) ? lcL1 : lcL0;
    float* clo = (i & 1) ? lcL0 : lcL1;
    float* cri = (i & 1) ? lcR1 : lcR0;
    float* cro = (i & 1) ? lcR0 : lcR1;
    step2_kernel<<<512, 256, 0, stream>>>(li, lo, ri, ro, cli, clo, cri, cro,
                                          hmap2, WnL, WnR, b_left, b_right);
  }
  // after 16 double-steps (32 steps), final state is in buffer 0
  final_kernel<<<256, 256, 0, stream>>>(x, lhL0, lhR0, WnS, b_skip, out);
}

// Round 4
// 440.981 us; speedup vs baseline: 6.1966x; 1.1956x over previous
//
#include <hip/hip_runtime.h>

// BiLSTM (diagonal, PixelRNN-style) on MI355X.
// R3: 1 step per launch, NO LDS / NO barriers in the step kernel.
// A-fragments are read directly from global lh (16B coalesced, predicated for
// boundary zeros); lc is single-buffered fp32 (pointwise, block-private);
// hmap packed [p][c][4gates] ushort4 -> one 8B load per pixel in epilogue.

using bf16   = __bf16;
using bf16x8 = __attribute__((ext_vector_type(8))) __bf16;
using f32x4  = __attribute__((ext_vector_type(4))) float;

__device__ __forceinline__ float sigf(float x) {
  return __builtin_amdgcn_rcpf(1.0f + __expf(-x));
}
__device__ __forceinline__ float tanh_fast(float x) {
  return 2.0f * __builtin_amdgcn_rcpf(1.0f + __expf(-2.0f * x)) - 1.0f;
}
__device__ __forceinline__ bf16x8 bzero8() {
  bf16x8 v;
#pragma unroll
  for (int e = 0; e < 8; ++e) v[e] = (bf16)0.0f;
  return v;
}
__device__ __forceinline__ unsigned short f2bu(float f) {
  bf16 b = (bf16)f;
  return __builtin_bit_cast(unsigned short, b);
}
__device__ __forceinline__ float bu2f(unsigned short u) {
  return __uint_as_float(((unsigned)u) << 16);
}

// ---------------- prep: weights -> bf16, [n][k] layouts ----------------
__global__ void prep_kernel(const float* __restrict__ w_i2s,
                            const float* __restrict__ w_left,
                            const float* __restrict__ w_right,
                            const float* __restrict__ w_skip,
                            bf16* __restrict__ WnI, bf16* __restrict__ WnL,
                            bf16* __restrict__ WnR, bf16* __restrict__ WnS) {
  int t = blockIdx.x * 256 + threadIdx.x;
  if (t < 32768) {
    WnI[t] = (bf16)w_i2s[t];  // [256][128] o-major == desired [n][k]
    int o = t >> 7, k = t & 127;
    // k<64: tap0 (h-1, w+-1) -> w[:,:,0]; k>=64: tap1 (h, w+-1) -> w[:,:,1]
    int src = (k < 64) ? (o * 128 + k * 2) : (o * 128 + (k - 64) * 2 + 1);
    WnL[t] = (bf16)w_left[src];
    WnR[t] = (bf16)w_right[src];
    if (t < 8192) WnS[t] = (bf16)w_skip[t];  // [128][64]
  }
}

// ------- hmap2 = pack(x @ w_i2s^T) : [p][c][4 gates] ushort4 (bf16 bits) -------
__global__ __launch_bounds__(256, 2)
void hmap_kernel(const float* __restrict__ x, const bf16* __restrict__ Wn,
                 ushort* __restrict__ hmap2) {
  __shared__ __align__(16) bf16 At[64 * 128];  // XOR-swizzled
  const int tile = blockIdx.x;  // 256 tiles: 64 px each (2 rows of one batch)
  const int b = tile >> 4, h0 = (tile & 15) << 1;
  const int t = threadIdx.x;
  const float* xb = x + (size_t)(b * 128) * 1024 + h0 * 32;
#pragma unroll
  for (int i = 0; i < 8; ++i) {
    int idx = t + 256 * i;          // [0,2048)
    int c = idx >> 4, m4 = idx & 15;
    f32x4 v = *(const f32x4*)(xb + (size_t)c * 1024 + m4 * 4);
#pragma unroll
    for (int e = 0; e < 4; ++e) {
      int m = m4 * 4 + e;
      int kb = (c * 2) ^ ((m & 7) << 4);
      *(bf16*)((char*)At + m * 256 + kb) = (bf16)v[e];
    }
  }
  __syncthreads();
  const int wv = t >> 6, l = t & 63;
  const int l15 = l & 15, lq = l >> 4;
  const int c = wv * 16 + l15;
  bf16x8 bfrag[4][4];
#pragma unroll
  for (int q = 0; q < 4; ++q)
#pragma unroll
    for (int kk = 0; kk < 4; ++kk)
      bfrag[q][kk] = *(const bf16x8*)(Wn + (q * 64 + c) * 128 + kk * 32 + lq * 8);
  f32x4 acc[4][4];
  const f32x4 fz = {0.f, 0.f, 0.f, 0.f};
#pragma unroll
  for (int ms = 0; ms < 4; ++ms)
#pragma unroll
    for (int q = 0; q < 4; ++q) acc[ms][q] = fz;
#pragma unroll
  for (int kk = 0; kk < 4; ++kk) {
#pragma unroll
    for (int ms = 0; ms < 4; ++ms) {
      int m = ms * 16 + l15;
      int kb = ((kk * 32 + lq * 8) * 2) ^ ((m & 7) << 4);
      bf16x8 a = *(const bf16x8*)((const char*)At + m * 256 + kb);
#pragma unroll
      for (int q = 0; q < 4; ++q)
        acc[ms][q] =
            __builtin_amdgcn_mfma_f32_16x16x32_bf16(a, bfrag[q][kk], acc[ms][q], 0, 0, 0);
    }
  }
  const int pix0 = tile * 64;
#pragma unroll
  for (int ms = 0; ms < 4; ++ms)
#pragma unroll
    for (int j = 0; j < 4; ++j) {
      int p = pix0 + ms * 16 + lq * 4 + j;
      ushort4 hv;
      hv.x = f2bu(acc[ms][0][j]);
      hv.y = f2bu(acc[ms][1][j]);
      hv.z = f2bu(acc[ms][2][j]);
      hv.w = f2bu(acc[ms][3][j]);
      ((ushort4*)hmap2)[(size_t)p * 64 + c] = hv;
    }
}

// ---------------- one scan step, no LDS, no barriers ----------------
// blocks [0,256): left stream; [256,512): right stream. Tile = 64 px (2 rows).
// A-row m: h = h0 + (ms>>1), w = (ms&1)*16 + l15. k = kk*32+lq*8:
//   kk 0,1 -> tap0 (row h-1), kk 2,3 -> tap1 (row h); c0 = (kk&1)*32 + lq*8.
__global__ __launch_bounds__(256, 2)
void step_kernel(const bf16* __restrict__ lhLin, bf16* __restrict__ lhLout,
                 const bf16* __restrict__ lhRin, bf16* __restrict__ lhRout,
                 float* __restrict__ lcL, float* __restrict__ lcR,
                 const ushort* __restrict__ hmap2,
                 const bf16* __restrict__ WnL, const bf16* __restrict__ WnR,
                 const float* __restrict__ bL, const float* __restrict__ bR) {
  const int blk = blockIdx.x;
  const bool right = blk >= 256;
  const int tile = right ? blk - 256 : blk;
  const bf16* __restrict__ lin = right ? lhRin : lhLin;
  bf16* __restrict__ lout = right ? lhRout : lhLout;
  float* __restrict__ lc = right ? lcR : lcL;
  const bf16* __restrict__ Wn = right ? WnR : WnL;
  const float* __restrict__ bias = right ? bR : bL;
  const int b = tile >> 4, h0 = (tile & 15) << 1;
  const int t = threadIdx.x;
  const int wv = t >> 6, l = t & 63, l15 = l & 15, lq = l >> 4;
  const int c = wv * 16 + l15;  // channel this lane owns (gate-interleaved N)
  const int dw = right ? 1 : -1;

  // B fragments: weights, L2-hot (same 32KB read by all blocks of a stream)
  bf16x8 bfrag[4][4];
#pragma unroll
  for (int q = 0; q < 4; ++q)
#pragma unroll
    for (int kk = 0; kk < 4; ++kk)
      bfrag[q][kk] = *(const bf16x8*)(Wn + (q * 64 + c) * 128 + kk * 32 + lq * 8);
  float bq[4];
#pragma unroll
  for (int q = 0; q < 4; ++q) bq[q] = bias[q * 64 + c];

  f32x4 acc[4][4];
  const f32x4 fz = {0.f, 0.f, 0.f, 0.f};
#pragma unroll
  for (int ms = 0; ms < 4; ++ms)
#pragma unroll
    for (int q = 0; q < 4; ++q) acc[ms][q] = fz;

  // GEMM with A-fragments loaded straight from global (predicated boundaries)
#pragma unroll
  for (int kk = 0; kk < 4; ++kk) {
    const int tap = kk >> 1;               // 0: row h-1, 1: row h
    const int c0 = (kk & 1) * 32 + lq * 8;
    bf16x8 af[4];
#pragma unroll
    for (int ms = 0; ms < 4; ++ms) {
      int h = h0 + (ms >> 1);
      int w = (ms & 1) * 16 + l15;
      int wsrc = w + dw;
      int hsrc = h - 1 + tap;
      bf16x8 v = bzero8();
      if ((unsigned)wsrc < 32u && hsrc >= 0)
        v = *(const bf16x8*)(lin + (size_t)((b * 32 + hsrc) * 32 + wsrc) * 64 + c0);
      af[ms] = v;
    }
#pragma unroll
    for (int ms = 0; ms < 4; ++ms)
#pragma unroll
      for (int q = 0; q < 4; ++q)
        acc[ms][q] =
            __builtin_amdgcn_mfma_f32_16x16x32_bf16(af[ms], bfrag[q][kk], acc[ms][q], 0, 0, 0);
  }

  // epilogue: all 4 gates of (p, c) live in this lane; lc single-buffered
  const int pix0 = tile * 64;
#pragma unroll
  for (int ms = 0; ms < 4; ++ms) {
#pragma unroll
    for (int j = 0; j < 4; ++j) {
      int p = pix0 + ms * 16 + lq * 4 + j;
      ushort4 hm = ((const ushort4*)hmap2)[(size_t)p * 64 + c];
      float lcold = lc[(size_t)p * 64 + c];
      float pre0 = acc[ms][0][j] + bu2f(hm.x) + bq[0];
      float pre1 = acc[ms][1][j] + bu2f(hm.y) + bq[1];
      float pre2 = acc[ms][2][j] + bu2f(hm.z) + bq[2];
      float pre3 = acc[ms][3][j] + bu2f(hm.w) + bq[3];
      float og = sigf(pre0), fg = sigf(pre1), ig = sigf(pre2), gg = sigf(pre3);
      float lcv = fg * lcold + ig * gg;
      lc[(size_t)p * 64 + c] = lcv;
      lout[(size_t)p * 64 + c] = (bf16)(og * tanh_fast(lcv));
    }
  }
}

// ---------------- final: out = x + (lhL + shift_down(lhR)) @ w_skip^T + b ----------------
__global__ __launch_bounds__(256, 2)
void final_kernel(const float* __restrict__ x, const bf16* __restrict__ lhL,
                  const bf16* __restrict__ lhR, const bf16* __restrict__ Wn,
                  const float* __restrict__ b_skip, float* __restrict__ out) {
  __shared__ __align__(16) bf16 At[64 * 64];
  __shared__ __align__(16) float smemT[128 * 72];  // [o2][m], padded rows
  const int tile = blockIdx.x;
  const int b = tile >> 4, h0 = (tile & 15) << 1;
  const int t = threadIdx.x;
#pragma unroll
  for (int i = 0; i < 2; ++i) {
    int idx = t + 256 * i;  // [0,512)
    int m = idx >> 3, c8 = idx & 7;
    int h = h0 + (m >> 5), w = m & 31;
    size_t p = (size_t)(b * 32 + h) * 32 + w;
    bf16x8 vL = *(const bf16x8*)(lhL + p * 64 + c8 * 8);
    bf16x8 v;
    if (h > 0) {
      bf16x8 vR = *(const bf16x8*)(lhR + (p - 32) * 64 + c8 * 8);
#pragma unroll
      for (int e = 0; e < 8; ++e) v[e] = (bf16)((float)vL[e] + (float)vR[e]);
    } else {
      v = vL;
    }
    int kb = (c8 * 16) ^ ((m & 7) << 4);
    *(bf16x8*)((char*)At + m * 128 + kb) = v;
  }
  __syncthreads();
  const int wv = t >> 6, l = t & 63;
  const int l15 = l & 15, lq = l >> 4;
  const int c = wv * 16 + l15;
  bf16x8 bfrag[2][2];
#pragma unroll
  for (int q = 0; q < 2; ++q)
#pragma unroll
    for (int kk = 0; kk < 2; ++kk)
      bfrag[q][kk] = *(const bf16x8*)(Wn + (q * 64 + c) * 64 + kk * 32 + lq * 8);
  f32x4 acc[4][2];
  const f32x4 fz = {0.f, 0.f, 0.f, 0.f};
#pragma unroll
  for (int ms = 0; ms < 4; ++ms)
#pragma unroll
    for (int q = 0; q < 2; ++q) acc[ms][q] = fz;
#pragma unroll
  for (int kk = 0; kk < 2; ++kk) {
#pragma unroll
    for (int ms = 0; ms < 4; ++ms) {
      int m = ms * 16 + l15;
      int kb = ((kk * 32 + lq * 8) * 2) ^ ((m & 7) << 4);
      bf16x8 a = *(const bf16x8*)((const char*)At + m * 128 + kb);
#pragma unroll
      for (int q = 0; q < 2; ++q)
        acc[ms][q] =
            __builtin_amdgcn_mfma_f32_16x16x32_bf16(a, bfrag[q][kk], acc[ms][q], 0, 0, 0);
    }
  }
  float bsk[2];
#pragma unroll
  for (int q = 0; q < 2; ++q) bsk[q] = b_skip[q * 64 + c];
#pragma unroll
  for (int ms = 0; ms < 4; ++ms)
#pragma unroll
    for (int q = 0; q < 2; ++q)
#pragma unroll
      for (int j = 0; j < 4; ++j) {
        int m = ms * 16 + lq * 4 + j;
        int n = q * 64 + c;
        smemT[n * 72 + m] = acc[ms][q][j] + bsk[q];
      }
  __syncthreads();
  const float* xb = x + (size_t)(b * 128) * 1024 + h0 * 32;
  float* ob = out + (size_t)(b * 128) * 1024 + h0 * 32;
#pragma unroll
  for (int i = 0; i < 8; ++i) {
    int idx = t + 256 * i;  // [0,2048)
    int o2 = idx >> 4, m4 = idx & 15;
    f32x4 s = *(const f32x4*)(&smemT[o2 * 72 + m4 * 4]);
    f32x4 xv = *(const f32x4*)(xb + (size_t)o2 * 1024 + m4 * 4);
#pragma unroll
    for (int e = 0; e < 4; ++e) s[e] += xv[e];
    *(f32x4*)(ob + (size_t)o2 * 1024 + m4 * 4) = s;
  }
}

extern "C" void kernel_launch(void* const* d_in, const int* in_sizes, int n_in,
                              void* d_out, int out_size, void* d_ws, size_t ws_size,
                              hipStream_t stream) {
  const float* x       = (const float*)d_in[0];
  const float* w_i2s   = (const float*)d_in[1];
  const float* w_left  = (const float*)d_in[2];
  const float* b_left  = (const float*)d_in[3];
  const float* w_right = (const float*)d_in[4];
  const float* b_right = (const float*)d_in[5];
  const float* w_skip  = (const float*)d_in[6];
  const float* b_skip  = (const float*)d_in[7];
  float* out = (float*)d_out;
  char* ws = (char*)d_ws;

  // ws layout (bytes); total ~24.3 MB
  bf16*   lhL0  = (bf16*)(ws + 0x0000000);   // 2 MB (zeroed)
  bf16*   lhR0  = (bf16*)(ws + 0x0200000);   // 2 MB (zeroed)
  float*  lcL   = (float*)(ws + 0x0400000);  // 4 MB (zeroed)
  float*  lcR   = (float*)(ws + 0x0800000);  // 4 MB (zeroed)
  bf16*   lhL1  = (bf16*)(ws + 0x0C00000);   // 2 MB
  bf16*   lhR1  = (bf16*)(ws + 0x0E00000);   // 2 MB
  ushort* hmap2 = (ushort*)(ws + 0x1000000); // 8 MB
  bf16*   WnI   = (bf16*)(ws + 0x1800000);   // 64 KB
  bf16*   WnL   = (bf16*)(ws + 0x1810000);
  bf16*   WnR   = (bf16*)(ws + 0x1820000);
  bf16*   WnS   = (bf16*)(ws + 0x1830000);

  // zero initial lh state + lc (one contiguous 12 MB region)
  hipMemsetAsync(ws, 0, 0x0C00000, stream);
  prep_kernel<<<128, 256, 0, stream>>>(w_i2s, w_left, w_right, w_skip, WnI, WnL, WnR, WnS);
  hmap_kernel<<<256, 256, 0, stream>>>(x, WnI, hmap2);
  for (int s = 0; s < 32; ++s) {
    bf16* liL = (s & 1) ? lhL1 : lhL0;
    bf16* loL = (s & 1) ? lhL0 : lhL1;
    bf16* liR = (s & 1) ? lhR1 : lhR0;
    bf16* loR = (s & 1) ? lhR0 : lhR1;
    step_kernel<<<512, 256, 0, stream>>>(liL, loL, liR, loR, lcL, lcR,
                                         hmap2, WnL, WnR, b_left, b_right);
  }
  // after 32 steps (s=31 writes buffer 0), final state is in buffer 0
  final_kernel<<<256, 256, 0, stream>>>(x, lhL0, lhR0, WnS, b_skip, out);
}